// Round 7
// baseline (340.626 us; speedup 1.0000x reference)
//
#include <hip/hip_runtime.h>
#include <hip/hip_bf16.h>
#include <math.h>

#define N_NODES 50000
#define N_EDGES 800000
#define N_GRAPHS 64
#define SCAN_BLOCKS 196   // ceil(50000/256)

typedef __attribute__((ext_vector_type(8))) short short8v;   // 8 bf16 (4 VGPRs)
typedef __attribute__((ext_vector_type(4))) float float4v;   // MFMA acc

// ---------------- workspace layout (bytes) ----------------
static constexpr size_t OFF_K1   = 0;            // bf16 [50000][128] (pre-scaled -log2e)
static constexpr size_t OFF_S1   = 12800000;     // bf16 [50000][128]
static constexpr size_t OFF_QV1  = 25600000;     // bf16 [50000][256] interleaved q',v
static constexpr size_t OFF_H1B  = 51200000;     // bf16 [50000][128]
static constexpr size_t OFF_XB   = 64000000;     // bf16 [50000][128]
// layer2 overlays layer1 buffers (K1/S1/QV1 dead after edge1):
static constexpr size_t OFF_K2   = 0;            // bf16 [50000][64] (pre-scaled)
static constexpr size_t OFF_S2   = 6400000;      // bf16 [50000][64]
static constexpr size_t OFF_QV2  = 12800000;     // bf16 [50000][128] interleaved
static constexpr size_t OFF_H2   = 25600000;     // f32 [50000][64]
static constexpr size_t OFF_ESRC = 76800000;     // 3.2 MB
static constexpr size_t OFF_OFFS = 80000000;     // 50001*4 -> pad
static constexpr size_t OFF_CURS = 80200064;     // 50000*4 (hist, then cursor)
static constexpr size_t OFF_BSUM = 80400064;     // 196*4
static constexpr size_t OFF_BBAS = 80400848;
static constexpr size_t OFF_BP1  = 80401664;     // bf16 packed 128*512
static constexpr size_t OFF_BC1  = 80532736;     // 512*4
static constexpr size_t OFF_BP2  = 80534784;     // bf16 packed 128*256
static constexpr size_t OFF_BC2  = 80600320;     // 256*4
static constexpr size_t OFF_SG   = 80601344;
static constexpr size_t OFF_EG   = 80601600;
static constexpr size_t OFF_PL   = 80601856;     // 64*64*4

#define NLOG2E 1.44269504f   // gate = rcp(1 + exp2(k' + q')), k'/q' pre-scaled by -log2e

__device__ inline unsigned short f2bf(float f) {
    __hip_bfloat16 h = __float2bfloat16(f);
    union { __hip_bfloat16 h; unsigned short u; } cv;
    cv.h = h;
    return cv.u;
}
__device__ inline float fast_exp2(float x) { float r; asm("v_exp_f32 %0, %1" : "=v"(r) : "v"(x)); return r; }
__device__ inline float fast_rcp (float x) { float r; asm("v_rcp_f32 %0, %1" : "=v"(r) : "v"(x)); return r; }
__device__ inline float u2f(unsigned int u) { union { unsigned int i; float f; } w; w.i = u; return w.f; }

// qv uint = [q' lo16 | v hi16]; accumulate 4 channels
__device__ inline void gacc4(uint4 qv, float k0, float k1, float k2, float k3, float* a) {
    float q0 = u2f(qv.x << 16), v0 = u2f(qv.x & 0xffff0000u);
    float q1 = u2f(qv.y << 16), v1 = u2f(qv.y & 0xffff0000u);
    float q2 = u2f(qv.z << 16), v2 = u2f(qv.z & 0xffff0000u);
    float q3 = u2f(qv.w << 16), v3 = u2f(qv.w & 0xffff0000u);
    a[0] += v0 * fast_rcp(1.f + fast_exp2(k0 + q0));
    a[1] += v1 * fast_rcp(1.f + fast_exp2(k1 + q1));
    a[2] += v2 * fast_rcp(1.f + fast_exp2(k2 + q2));
    a[3] += v3 * fast_rcp(1.f + fast_exp2(k3 + q3));
}

// ---------------- x -> bf16 cast ----------------
__global__ void cast_kernel(const float* __restrict__ x, unsigned short* __restrict__ xb) {
    int id = blockIdx.x * 256 + threadIdx.x;
    float4 v0 = *(const float4*)&x[(size_t)id * 8];
    float4 v1 = *(const float4*)&x[(size_t)id * 8 + 4];
    short8v o;
    o[0] = (short)f2bf(v0.x); o[1] = (short)f2bf(v0.y);
    o[2] = (short)f2bf(v0.z); o[3] = (short)f2bf(v0.w);
    o[4] = (short)f2bf(v1.x); o[5] = (short)f2bf(v1.y);
    o[6] = (short)f2bf(v1.z); o[7] = (short)f2bf(v1.w);
    *(short8v*)(xb + (size_t)id * 8) = o;
}

// ---------------- weight prep: pack into MFMA B-fragment order ----------------
__global__ void prep1_kernel(const float* __restrict__ wk, const float* __restrict__ bk,
                             const float* __restrict__ wq, const float* __restrict__ bq,
                             const float* __restrict__ wv, const float* __restrict__ bv,
                             const float* __restrict__ ws, const float* __restrict__ bs,
                             unsigned short* __restrict__ Bp, float* __restrict__ bcat) {
    int id = blockIdx.x * 256 + threadIdx.x;      // 8192 total
    if (id < 8192) {
        int l = id & 63, ks = (id >> 6) & 3, ct = id >> 8;
        int c = ct * 16 + (l & 15);
        int g = c >> 7, n = c & 127;
        const float* W = (g == 0) ? wk : (g == 1) ? wq : (g == 2) ? wv : ws;
        int kb = ks * 32 + ((l >> 4) << 3);
        short8v o;
#pragma unroll
        for (int j = 0; j < 8; ++j) o[j] = (short)f2bf(W[n * 128 + kb + j]);
        *(short8v*)(Bp + (size_t)id * 8) = o;
    }
    if (id < 512) {
        int g = id >> 7, n = id & 127;
        const float* B = (g == 0) ? bk : (g == 1) ? bq : (g == 2) ? bv : bs;
        bcat[id] = B[n];
    }
}

__global__ void prep2_kernel(const float* __restrict__ wk, const float* __restrict__ bk,
                             const float* __restrict__ wq, const float* __restrict__ bq,
                             const float* __restrict__ wv, const float* __restrict__ bv,
                             const float* __restrict__ ws, const float* __restrict__ bs,
                             unsigned short* __restrict__ Bp, float* __restrict__ bcat) {
    int id = blockIdx.x * 256 + threadIdx.x;      // 4096 total
    if (id < 4096) {
        int l = id & 63, ks = (id >> 6) & 3, ct = id >> 8;
        int c = ct * 16 + (l & 15);
        int g = c >> 6, n = c & 63;
        const float* W = (g == 0) ? wk : (g == 1) ? wq : (g == 2) ? wv : ws;
        int kb = ks * 32 + ((l >> 4) << 3);
        short8v o;
#pragma unroll
        for (int j = 0; j < 8; ++j) o[j] = (short)f2bf(W[n * 128 + kb + j]);
        *(short8v*)(Bp + (size_t)id * 8) = o;
    }
    if (id < 256) {
        int g = id >> 6, n = id & 63;
        const float* B = (g == 0) ? bk : (g == 1) ? bq : (g == 2) ? bv : bs;
        bcat[id] = B[n];
    }
}

// ---------------- CSR build ----------------
__global__ void hist_kernel(const int* __restrict__ dst, int* __restrict__ hist) {
    int e = blockIdx.x * 256 + threadIdx.x;
    if (e < N_EDGES) atomicAdd(&hist[dst[e]], 1);
}

__global__ void bsum_kernel(const int* __restrict__ hist, int* __restrict__ bsum) {
    int t = threadIdx.x;
    int idx = blockIdx.x * 256 + t;
    __shared__ int sh[256];
    sh[t] = (idx < N_NODES) ? hist[idx] : 0;
    __syncthreads();
    for (int d = 128; d > 0; d >>= 1) {
        if (t < d) sh[t] += sh[t + d];
        __syncthreads();
    }
    if (t == 0) bsum[blockIdx.x] = sh[0];
}

__global__ void bscan_kernel(const int* __restrict__ bsum, int* __restrict__ bbase) {
    int t = threadIdx.x;   // 256
    __shared__ int sh[256];
    sh[t] = (t < SCAN_BLOCKS) ? bsum[t] : 0;
    __syncthreads();
    for (int d = 1; d < 256; d <<= 1) {
        int v = (t >= d) ? sh[t - d] : 0;
        __syncthreads();
        sh[t] += v;
        __syncthreads();
    }
    if (t < SCAN_BLOCKS) bbase[t] = (t == 0) ? 0 : sh[t - 1];
}

__global__ void offs_kernel(const int* __restrict__ hist, const int* __restrict__ bbase,
                            int* __restrict__ offs, int* __restrict__ cursor) {
    int t = threadIdx.x;
    int idx = blockIdx.x * 256 + t;
    int v = (idx < N_NODES) ? hist[idx] : 0;
    __shared__ int sh[256];
    sh[t] = v;
    __syncthreads();
    for (int d = 1; d < 256; d <<= 1) {
        int u = (t >= d) ? sh[t - d] : 0;
        __syncthreads();
        sh[t] += u;
        __syncthreads();
    }
    if (idx < N_NODES) {
        int o = bbase[blockIdx.x] + sh[t] - v;   // exclusive
        offs[idx] = o;
        cursor[idx] = o;
    }
    if (idx == 0) offs[N_NODES] = N_EDGES;
}

__global__ void fill_kernel(const int* __restrict__ src, const int* __restrict__ dst,
                            int* __restrict__ cursor, int* __restrict__ esrc) {
    int e = blockIdx.x * 256 + threadIdx.x;
    if (e < N_EDGES) {
        int d = dst[e];
        int pos = atomicAdd(&cursor[d], 1);
        esrc[pos] = src[e];
    }
}

// ---------------- layer1 MFMA GEMM, paired col-tiles, LDS-staged epilogue ----------------
// blockIdx.y==0: K (ct0-7, scaled) + S (ct24-31)  -> plane outputs [M][128] bf16
// blockIdx.y==1: Q (ct8-15, scaled) + V (ct16-23) -> interleaved QV [M][256] bf16
__global__ __launch_bounds__(256) void gemm1_kernel(const unsigned short* __restrict__ Ab,
                                                    const unsigned short* __restrict__ Bp,
                                                    const float* __restrict__ bias,
                                                    unsigned short* __restrict__ Kout,
                                                    unsigned short* __restrict__ Sout,
                                                    unsigned short* __restrict__ QVout,
                                                    int M) {
    __shared__ __align__(16) unsigned char As[32768];
    const int tid = threadIdx.x;
    const int w = tid >> 6, l = tid & 63;
    const int lx = l & 15, lg = l >> 4;
    const int row0 = blockIdx.x * 128;
    const bool isKS = (blockIdx.y == 0);

    // stage A tile (128x128 bf16), swizzled 16B chunks
#pragma unroll
    for (int i = 0; i < 8; ++i) {
        int id = i * 256 + tid;
        int r = id >> 4, c = id & 15;
        int gr = row0 + r;
        short8v v;
#pragma unroll
        for (int j = 0; j < 8; ++j) v[j] = 0;
        if (gr < M) v = *(const short8v*)(Ab + (size_t)gr * 128 + c * 8);
        *(short8v*)(As + r * 256 + ((c ^ (r & 7)) << 4)) = v;
    }
    __syncthreads();

    float4v acc[2][16];
#pragma unroll
    for (int m = 0; m < 2; ++m)
#pragma unroll
        for (int n = 0; n < 16; ++n)
#pragma unroll
            for (int q = 0; q < 4; ++q) acc[m][n][q] = 0.f;

    const int ctA = isKS ? 0 : 8;
    const int ctB = isKS ? 24 : 16;
#pragma unroll
    for (int ks = 0; ks < 4; ++ks) {
        short8v a[2];
#pragma unroll
        for (int m = 0; m < 2; ++m) {
            int rl = 32 * w + 16 * m + lx;
            int cc = ks * 4 + lg;
            a[m] = *(const short8v*)(As + rl * 256 + ((cc ^ (rl & 7)) << 4));
        }
#pragma unroll
        for (int n = 0; n < 16; ++n) {
            int ct = (n < 8) ? (ctA + n) : (ctB + n - 8);
            short8v b = *(const short8v*)(Bp + (size_t)((ct * 4 + ks) * 64 + l) * 8);
            acc[0][n] = __builtin_amdgcn_mfma_f32_16x16x32_bf16(a[0], b, acc[0][n], 0, 0, 0);
            acc[1][n] = __builtin_amdgcn_mfma_f32_16x16x32_bf16(a[1], b, acc[1][n], 0, 0, 0);
        }
    }

    const int colA0 = isKS ? 0 : 128;
    const int colB0 = isKS ? 384 : 256;
    float bbA[8], bbB[8];
#pragma unroll
    for (int n = 0; n < 8; ++n) {
        bbA[n] = bias[colA0 + 16 * n + lx];
        bbB[n] = bias[colB0 + 16 * n + lx];
    }

    const int rl0 = 32 * w + 4 * lg;
    if (isKS) {
        for (int plane = 0; plane < 2; ++plane) {
            __syncthreads();
#pragma unroll
            for (int m = 0; m < 2; ++m)
#pragma unroll
                for (int reg = 0; reg < 4; ++reg) {
                    int r = rl0 + 16 * m + reg;
#pragma unroll
                    for (int n = 0; n < 8; ++n) {
                        float val = acc[m][plane * 8 + n][reg] + (plane ? bbB[n] : bbA[n]);
                        if (plane == 0) val = -NLOG2E * val;
                        int c = 16 * n + lx;
                        int off = r * 256 + (((c >> 3) ^ (r & 7)) << 4) + ((c & 7) << 1);
                        *(unsigned short*)(As + off) = f2bf(val);
                    }
                }
            __syncthreads();
            unsigned short* Out = plane ? Sout : Kout;
#pragma unroll
            for (int i = 0; i < 8; ++i) {
                int id = i * 256 + tid;
                int row = id >> 4, k = id & 15;
                int gr = row0 + row;
                if (gr < M) {
                    short8v v = *(const short8v*)(As + row * 256 + ((k ^ (row & 7)) << 4));
                    *(short8v*)(Out + (size_t)gr * 128 + k * 8) = v;
                }
            }
        }
    } else {
        for (int h = 0; h < 2; ++h) {
            __syncthreads();
#pragma unroll
            for (int m = 0; m < 2; ++m)
#pragma unroll
                for (int reg = 0; reg < 4; ++reg) {
                    int r = rl0 + 16 * m + reg;
                    if ((r >> 6) == h) {
                        int rr = r & 63;
#pragma unroll
                        for (int n = 0; n < 8; ++n) {
                            float qval = -NLOG2E * (acc[m][n][reg] + bbA[n]);
                            float vval = acc[m][8 + n][reg] + bbB[n];
                            int c = 16 * n + lx;
                            int off = rr * 512 + (((c >> 2) ^ (rr & 7)) << 4) + ((c & 3) << 2);
                            *(unsigned short*)(As + off)     = f2bf(qval);
                            *(unsigned short*)(As + off + 2) = f2bf(vval);
                        }
                    }
                }
            __syncthreads();
#pragma unroll
            for (int i = 0; i < 8; ++i) {
                int id = i * 256 + tid;
                int row = id >> 5, k = id & 31;
                int gr = row0 + h * 64 + row;
                if (gr < M) {
                    short8v v = *(const short8v*)(As + row * 512 + ((k ^ (row & 7)) << 4));
                    *(short8v*)(QVout + (size_t)gr * 256 + k * 8) = v;
                }
            }
        }
    }
}

// ---------------- layer2 MFMA GEMM, single block computes K,Q,V,S ----------------
// ct: K 0-3 (scaled), Q 4-7 (scaled), V 8-11, S 12-15
__global__ __launch_bounds__(256) void gemm2_kernel(const unsigned short* __restrict__ Ab,
                                                    const unsigned short* __restrict__ Bp,
                                                    const float* __restrict__ bias,
                                                    unsigned short* __restrict__ Kout,
                                                    unsigned short* __restrict__ Sout,
                                                    unsigned short* __restrict__ QVout,
                                                    int M) {
    __shared__ __align__(16) unsigned char As[32768];
    const int tid = threadIdx.x;
    const int w = tid >> 6, l = tid & 63;
    const int lx = l & 15, lg = l >> 4;
    const int row0 = blockIdx.x * 128;

#pragma unroll
    for (int i = 0; i < 8; ++i) {
        int id = i * 256 + tid;
        int r = id >> 4, c = id & 15;
        int gr = row0 + r;
        short8v v;
#pragma unroll
        for (int j = 0; j < 8; ++j) v[j] = 0;
        if (gr < M) v = *(const short8v*)(Ab + (size_t)gr * 128 + c * 8);
        *(short8v*)(As + r * 256 + ((c ^ (r & 7)) << 4)) = v;
    }
    __syncthreads();

    float4v acc[2][16];
#pragma unroll
    for (int m = 0; m < 2; ++m)
#pragma unroll
        for (int n = 0; n < 16; ++n)
#pragma unroll
            for (int q = 0; q < 4; ++q) acc[m][n][q] = 0.f;

#pragma unroll
    for (int ks = 0; ks < 4; ++ks) {
        short8v a[2];
#pragma unroll
        for (int m = 0; m < 2; ++m) {
            int rl = 32 * w + 16 * m + lx;
            int cc = ks * 4 + lg;
            a[m] = *(const short8v*)(As + rl * 256 + ((cc ^ (rl & 7)) << 4));
        }
#pragma unroll
        for (int n = 0; n < 16; ++n) {
            short8v b = *(const short8v*)(Bp + (size_t)((n * 4 + ks) * 64 + l) * 8);
            acc[0][n] = __builtin_amdgcn_mfma_f32_16x16x32_bf16(a[0], b, acc[0][n], 0, 0, 0);
            acc[1][n] = __builtin_amdgcn_mfma_f32_16x16x32_bf16(a[1], b, acc[1][n], 0, 0, 0);
        }
    }

    float bbk[4], bbq[4], bbv[4], bbs[4];
#pragma unroll
    for (int n = 0; n < 4; ++n) {
        bbk[n] = bias[16 * n + lx];
        bbq[n] = bias[64 + 16 * n + lx];
        bbv[n] = bias[128 + 16 * n + lx];
        bbs[n] = bias[192 + 16 * n + lx];
    }

    const int rl0 = 32 * w + 4 * lg;
    // pass 1: K (As[0..16K)) and S (As[16K..32K)), rows of 128 B
    __syncthreads();
#pragma unroll
    for (int m = 0; m < 2; ++m)
#pragma unroll
        for (int reg = 0; reg < 4; ++reg) {
            int r = rl0 + 16 * m + reg;
#pragma unroll
            for (int n = 0; n < 4; ++n) {
                int c = 16 * n + lx;
                int off = r * 128 + (((c >> 3) ^ (r & 7)) << 4) + ((c & 7) << 1);
                float kv = -NLOG2E * (acc[m][n][reg] + bbk[n]);
                float sv = acc[m][12 + n][reg] + bbs[n];
                *(unsigned short*)(As + off)         = f2bf(kv);
                *(unsigned short*)(As + 16384 + off) = f2bf(sv);
            }
        }
    __syncthreads();
#pragma unroll
    for (int i = 0; i < 8; ++i) {
        int id = i * 256 + tid;      // 0..2047: first 1024 K, next 1024 S
        int half = id >> 10;
        int id2 = id & 1023;
        int row = id2 >> 3, k = id2 & 7;
        int gr = row0 + row;
        if (gr < M) {
            short8v v = *(const short8v*)(As + half * 16384 + row * 128 + ((k ^ (row & 7)) << 4));
            unsigned short* Out = half ? Sout : Kout;
            *(short8v*)(Out + (size_t)gr * 64 + k * 8) = v;
        }
    }
    // pass 2: QV interleaved, rows of 256 B
    __syncthreads();
#pragma unroll
    for (int m = 0; m < 2; ++m)
#pragma unroll
        for (int reg = 0; reg < 4; ++reg) {
            int r = rl0 + 16 * m + reg;
#pragma unroll
            for (int n = 0; n < 4; ++n) {
                int c = 16 * n + lx;
                int off = r * 256 + (((c >> 2) ^ (r & 7)) << 4) + ((c & 3) << 2);
                float qv_ = -NLOG2E * (acc[m][4 + n][reg] + bbq[n]);
                float vv  = acc[m][8 + n][reg] + bbv[n];
                *(unsigned short*)(As + off)     = f2bf(qv_);
                *(unsigned short*)(As + off + 2) = f2bf(vv);
            }
        }
    __syncthreads();
#pragma unroll
    for (int i = 0; i < 8; ++i) {
        int id = i * 256 + tid;
        int row = id >> 4, k = id & 15;
        int gr = row0 + row;
        if (gr < M) {
            short8v v = *(const short8v*)(As + row * 256 + ((k ^ (row & 7)) << 4));
            *(short8v*)(QVout + (size_t)gr * 128 + k * 8) = v;
        }
    }
}

// ---------------- edge aggregation: 2 edges/wave, 8 in flight ----------------
__global__ __launch_bounds__(256) void edge1_kernel(const unsigned short* __restrict__ K1b,
                                                    const unsigned short* __restrict__ S1b,
                                                    const unsigned int* __restrict__ QV,
                                                    const int* __restrict__ offs,
                                                    const int* __restrict__ esrc,
                                                    unsigned short* __restrict__ H1B) {
    int node = __builtin_amdgcn_readfirstlane(blockIdx.x * 4 + (threadIdx.x >> 6));
    int lane = threadIdx.x & 63;
    int half = lane >> 5, cl = lane & 31;    // lane handles ch 4cl..4cl+3 of edge (j+half)
    uint2 kk = *(const uint2*)(K1b + (size_t)node * 128 + cl * 4);
    uint2 ss = *(const uint2*)(S1b + (size_t)node * 128 + cl * 4);
    float k0 = u2f(kk.x << 16), k1 = u2f(kk.x & 0xffff0000u);
    float k2 = u2f(kk.y << 16), k3 = u2f(kk.y & 0xffff0000u);
    float a0[4] = {0.f, 0.f, 0.f, 0.f};
    float a1[4] = {0.f, 0.f, 0.f, 0.f};
    int e0 = offs[node], e1 = offs[node + 1];
    int j = e0;
    for (; j + 8 <= e1; j += 8) {
        int s0 = esrc[j + 0 + half];
        int s1 = esrc[j + 2 + half];
        int s2 = esrc[j + 4 + half];
        int s3 = esrc[j + 6 + half];
        uint4 g0 = *(const uint4*)(QV + (size_t)s0 * 128 + cl * 4);
        uint4 g1 = *(const uint4*)(QV + (size_t)s1 * 128 + cl * 4);
        uint4 g2 = *(const uint4*)(QV + (size_t)s2 * 128 + cl * 4);
        uint4 g3 = *(const uint4*)(QV + (size_t)s3 * 128 + cl * 4);
        gacc4(g0, k0, k1, k2, k3, a0);
        gacc4(g1, k0, k1, k2, k3, a1);
        gacc4(g2, k0, k1, k2, k3, a0);
        gacc4(g3, k0, k1, k2, k3, a1);
    }
    for (; j < e1; j += 2) {
        int jj = j + half;
        if (jj < e1) {
            int s = esrc[jj];
            uint4 g = *(const uint4*)(QV + (size_t)s * 128 + cl * 4);
            gacc4(g, k0, k1, k2, k3, a0);
        }
    }
    float t0 = a0[0] + a1[0], t1 = a0[1] + a1[1];
    float t2 = a0[2] + a1[2], t3 = a0[3] + a1[3];
    t0 += __shfl_xor(t0, 32);
    t1 += __shfl_xor(t1, 32);
    t2 += __shfl_xor(t2, 32);
    t3 += __shfl_xor(t3, 32);
    if (half == 0) {
        float s0 = u2f(ss.x << 16), s1 = u2f(ss.x & 0xffff0000u);
        float s2 = u2f(ss.y << 16), s3 = u2f(ss.y & 0xffff0000u);
        float r0 = s0 + t0, r1 = s1 + t1, r2 = s2 + t2, r3 = s3 + t3;
        ushort4 o;
        o.x = f2bf(r0 > 0.f ? r0 : 0.f);
        o.y = f2bf(r1 > 0.f ? r1 : 0.f);
        o.z = f2bf(r2 > 0.f ? r2 : 0.f);
        o.w = f2bf(r3 > 0.f ? r3 : 0.f);
        *(ushort4*)(H1B + (size_t)node * 128 + cl * 4) = o;
    }
}

// 4 edges/wave (16-lane groups), 8 in flight
__global__ __launch_bounds__(256) void edge2_kernel(const unsigned short* __restrict__ K2b,
                                                    const unsigned short* __restrict__ S2b,
                                                    const unsigned int* __restrict__ QV,
                                                    const int* __restrict__ offs,
                                                    const int* __restrict__ esrc,
                                                    float* __restrict__ H2) {
    int node = __builtin_amdgcn_readfirstlane(blockIdx.x * 4 + (threadIdx.x >> 6));
    int lane = threadIdx.x & 63;
    int quart = lane >> 4, cl = lane & 15;   // ch 4cl..4cl+3 of edge (j+quart)
    uint2 kk = *(const uint2*)(K2b + (size_t)node * 64 + cl * 4);
    uint2 ss = *(const uint2*)(S2b + (size_t)node * 64 + cl * 4);
    float k0 = u2f(kk.x << 16), k1 = u2f(kk.x & 0xffff0000u);
    float k2 = u2f(kk.y << 16), k3 = u2f(kk.y & 0xffff0000u);
    float a0[4] = {0.f, 0.f, 0.f, 0.f};
    float a1[4] = {0.f, 0.f, 0.f, 0.f};
    int e0 = offs[node], e1 = offs[node + 1];
    int j = e0;
    for (; j + 8 <= e1; j += 8) {
        int s0 = esrc[j + quart];
        int s1 = esrc[j + 4 + quart];
        uint4 g0 = *(const uint4*)(QV + (size_t)s0 * 64 + cl * 4);
        uint4 g1 = *(const uint4*)(QV + (size_t)s1 * 64 + cl * 4);
        gacc4(g0, k0, k1, k2, k3, a0);
        gacc4(g1, k0, k1, k2, k3, a1);
    }
    for (; j < e1; j += 4) {
        int jj = j + quart;
        if (jj < e1) {
            int s = esrc[jj];
            uint4 g = *(const uint4*)(QV + (size_t)s * 64 + cl * 4);
            gacc4(g, k0, k1, k2, k3, a0);
        }
    }
    float t0 = a0[0] + a1[0], t1 = a0[1] + a1[1];
    float t2 = a0[2] + a1[2], t3 = a0[3] + a1[3];
    t0 += __shfl_xor(t0, 16); t0 += __shfl_xor(t0, 32);
    t1 += __shfl_xor(t1, 16); t1 += __shfl_xor(t1, 32);
    t2 += __shfl_xor(t2, 16); t2 += __shfl_xor(t2, 32);
    t3 += __shfl_xor(t3, 16); t3 += __shfl_xor(t3, 32);
    if (quart == 0) {
        float s0 = u2f(ss.x << 16), s1 = u2f(ss.x & 0xffff0000u);
        float s2 = u2f(ss.y << 16), s3 = u2f(ss.y & 0xffff0000u);
        float4 o;
        o.x = fmaxf(s0 + t0, 0.f);
        o.y = fmaxf(s1 + t1, 0.f);
        o.z = fmaxf(s2 + t2, 0.f);
        o.w = fmaxf(s3 + t3, 0.f);
        *(float4*)(H2 + (size_t)node * 64 + cl * 4) = o;
    }
}

// ---------------- pooling ----------------
__global__ void bounds_kernel(const int* __restrict__ batch, int* __restrict__ sg,
                              int* __restrict__ eg) {
    int n = blockIdx.x * 256 + threadIdx.x;
    if (n >= N_NODES) return;
    int b = batch[n];
    if (n == 0) {
        sg[b] = 0;
    } else {
        int p = batch[n - 1];
        if (p != b) { sg[b] = n; eg[p] = n - 1; }
    }
    if (n == N_NODES - 1) eg[b] = N_NODES - 1;
}

__global__ void pool_kernel(const float* __restrict__ H2, const int* __restrict__ sg,
                            const int* __restrict__ eg, float* __restrict__ pooled) {
    int g = blockIdx.x;
    int s = sg[g], e = eg[g];
    int ch = threadIdx.x & 63, sub = threadIdx.x >> 6;
    float acc = 0.f;
    for (int n = s + sub; n <= e; n += 4) acc += H2[(size_t)n * 64 + ch];
    __shared__ float red[4][64];
    red[sub][ch] = acc;
    __syncthreads();
    if (sub == 0) {
        float v = red[0][ch] + red[1][ch] + red[2][ch] + red[3][ch];
        int cnt = e - s + 1;
        if (cnt < 1) cnt = 1;
        pooled[g * 64 + ch] = v / (float)cnt;
    }
}

__global__ void fc_kernel(const float* __restrict__ pooled, const float* __restrict__ wfc,
                          const float* __restrict__ bfc, float* __restrict__ out) {
    int t = threadIdx.x;          // 128
    int g = t >> 1, c = t & 1;
    float s = bfc[c];
#pragma unroll
    for (int i = 0; i < 64; ++i) s += pooled[g * 64 + i] * wfc[c * 64 + i];
    out[g * 2 + c] = s;
}

// ---------------- launch ----------------
extern "C" void kernel_launch(void* const* d_in, const int* in_sizes, int n_in,
                              void* d_out, int out_size, void* d_ws, size_t ws_size,
                              hipStream_t stream) {
    (void)in_sizes; (void)n_in; (void)out_size; (void)ws_size;
    const float* x    = (const float*)d_in[0];
    const int*   ei   = (const int*)d_in[1];
    const int*   batch= (const int*)d_in[2];
    const float* w1k = (const float*)d_in[3];  const float* b1k = (const float*)d_in[4];
    const float* w1q = (const float*)d_in[5];  const float* b1q = (const float*)d_in[6];
    const float* w1v = (const float*)d_in[7];  const float* b1v = (const float*)d_in[8];
    const float* w1s = (const float*)d_in[9];  const float* b1s = (const float*)d_in[10];
    const float* w2k = (const float*)d_in[11]; const float* b2k = (const float*)d_in[12];
    const float* w2q = (const float*)d_in[13]; const float* b2q = (const float*)d_in[14];
    const float* w2v = (const float*)d_in[15]; const float* b2v = (const float*)d_in[16];
    const float* w2s = (const float*)d_in[17]; const float* b2s = (const float*)d_in[18];
    const float* wfc = (const float*)d_in[19]; const float* bfc = (const float*)d_in[20];
    float* out = (float*)d_out;

    char* ws = (char*)d_ws;
    unsigned short* K1  = (unsigned short*)(ws + OFF_K1);
    unsigned short* S1  = (unsigned short*)(ws + OFF_S1);
    unsigned short* QV1 = (unsigned short*)(ws + OFF_QV1);
    unsigned short* H1B = (unsigned short*)(ws + OFF_H1B);
    unsigned short* XB  = (unsigned short*)(ws + OFF_XB);
    unsigned short* K2  = (unsigned short*)(ws + OFF_K2);
    unsigned short* S2  = (unsigned short*)(ws + OFF_S2);
    unsigned short* QV2 = (unsigned short*)(ws + OFF_QV2);
    float* H2   = (float*)(ws + OFF_H2);
    int*   esrc = (int*)(ws + OFF_ESRC);
    int*   offs = (int*)(ws + OFF_OFFS);
    int*   curs = (int*)(ws + OFF_CURS);
    int*   bsum = (int*)(ws + OFF_BSUM);
    int*   bbas = (int*)(ws + OFF_BBAS);
    unsigned short* BP1 = (unsigned short*)(ws + OFF_BP1);
    float* bc1  = (float*)(ws + OFF_BC1);
    unsigned short* BP2 = (unsigned short*)(ws + OFF_BP2);
    float* bc2  = (float*)(ws + OFF_BC2);
    int*   sg   = (int*)(ws + OFF_SG);
    int*   eg   = (int*)(ws + OFF_EG);
    float* pl   = (float*)(ws + OFF_PL);

    const int* src = ei;
    const int* dst = ei + N_EDGES;

    // prep
    prep1_kernel<<<32, 256, 0, stream>>>(w1k, b1k, w1q, b1q, w1v, b1v, w1s, b1s, BP1, bc1);
    prep2_kernel<<<16, 256, 0, stream>>>(w2k, b2k, w2q, b2q, w2v, b2v, w2s, b2s, BP2, bc2);
    cast_kernel<<<3125, 256, 0, stream>>>(x, XB);

    // CSR build (by dst), hierarchical scan
    hipMemsetAsync(curs, 0, N_NODES * sizeof(int), stream);
    hist_kernel<<<(N_EDGES + 255) / 256, 256, 0, stream>>>(dst, curs);
    bsum_kernel<<<SCAN_BLOCKS, 256, 0, stream>>>(curs, bsum);
    bscan_kernel<<<1, 256, 0, stream>>>(bsum, bbas);
    offs_kernel<<<SCAN_BLOCKS, 256, 0, stream>>>(curs, bbas, offs, curs);
    fill_kernel<<<(N_EDGES + 255) / 256, 256, 0, stream>>>(src, dst, curs, esrc);

    // layer 1
    gemm1_kernel<<<dim3(391, 2), 256, 0, stream>>>(XB, BP1, bc1, K1, S1, QV1, N_NODES);
    edge1_kernel<<<12500, 256, 0, stream>>>(K1, S1, (const unsigned int*)QV1, offs, esrc, H1B);

    // layer 2
    gemm2_kernel<<<391, 256, 0, stream>>>(H1B, BP2, bc2, K2, S2, QV2, N_NODES);
    edge2_kernel<<<12500, 256, 0, stream>>>(K2, S2, (const unsigned int*)QV2, offs, esrc, H2);

    // pooling + fc
    hipMemsetAsync(sg, 0x7f, N_GRAPHS * sizeof(int), stream);
    hipMemsetAsync(eg, 0x80, N_GRAPHS * sizeof(int), stream);
    bounds_kernel<<<(N_NODES + 255) / 256, 256, 0, stream>>>(batch, sg, eg);
    pool_kernel<<<N_GRAPHS, 256, 0, stream>>>(H2, sg, eg, pl);
    fc_kernel<<<1, 128, 0, stream>>>(pl, wfc, bfc, out);
}